// Round 3
// baseline (1169.028 us; speedup 1.0000x reference)
//
#include <hip/hip_runtime.h>
#include <hip/hip_bf16.h>
#include <math.h>

#define N_NODES 100000
#define N_EDGES 1600000
#define F_IN 15
#define H1 64
#define H2 32
#define BN_EPS 1e-5f

// ---------------- CSR build ----------------

__global__ void k_deg(const int* __restrict__ dst, int* __restrict__ deg) {
    int e = blockIdx.x * blockDim.x + threadIdx.x;
    if (e < N_EDGES) atomicAdd(&deg[dst[e]], 1);
}

__global__ void k_scan_a(const int* __restrict__ deg, int* __restrict__ off,
                         int* __restrict__ part) {
    __shared__ int s[1024];
    int i = blockIdx.x * 1024 + threadIdx.x;
    int v = (i < N_NODES) ? deg[i] : 0;
    s[threadIdx.x] = v;
    __syncthreads();
    for (int o = 1; o < 1024; o <<= 1) {
        int t = (threadIdx.x >= o) ? s[threadIdx.x - o] : 0;
        __syncthreads();
        s[threadIdx.x] += t;
        __syncthreads();
    }
    if (i < N_NODES) off[i] = s[threadIdx.x] - v;   // block-local exclusive
    if (threadIdx.x == 1023) part[blockIdx.x] = s[1023];
}

__global__ void k_scan_b(int* __restrict__ part, int nb) {
    __shared__ int s[128];
    int v = (threadIdx.x < nb) ? part[threadIdx.x] : 0;
    s[threadIdx.x] = v;
    __syncthreads();
    for (int o = 1; o < 128; o <<= 1) {
        int t = (threadIdx.x >= o) ? s[threadIdx.x - o] : 0;
        __syncthreads();
        s[threadIdx.x] += t;
        __syncthreads();
    }
    if (threadIdx.x < nb) part[threadIdx.x] = s[threadIdx.x] - v;  // exclusive base
}

__global__ void k_scan_c(int* __restrict__ off, int* __restrict__ cur,
                         const int* __restrict__ part) {
    int i = blockIdx.x * blockDim.x + threadIdx.x;
    if (i < N_NODES) {
        int v = off[i] + part[i >> 10];
        off[i] = v;
        cur[i] = v;
    }
    if (i == 0) off[N_NODES] = N_EDGES;
}

__global__ void k_fill(const int* __restrict__ src, const int* __restrict__ dst,
                       int* __restrict__ cur, int* __restrict__ srt) {
    int e = blockIdx.x * blockDim.x + threadIdx.x;
    if (e < N_EDGES) {
        int p = atomicAdd(&cur[dst[e]], 1);
        srt[p] = src[e];
    }
}

// ---------------- Layer 1: thread-per-node, d=15 -> 64 ----------------
// h1_pre = mean(x[nbrs]) @ W1l.T + b1l + x @ W1r.T ; accumulate BN stats.

__launch_bounds__(256)
__global__ void k_l1(const float* __restrict__ x, const int* __restrict__ off,
                     const int* __restrict__ srt,
                     const float* __restrict__ W1l, const float* __restrict__ b1l,
                     const float* __restrict__ W1r,
                     float* __restrict__ h1, float* __restrict__ stats) {
    __shared__ float wl[H1][16], wr[H1][16], bias[H1];
    __shared__ float sred[2 * H1];
    for (int idx = threadIdx.x; idx < H1 * F_IN; idx += 256) {
        wl[idx / F_IN][idx % F_IN] = W1l[idx];
        wr[idx / F_IN][idx % F_IN] = W1r[idx];
    }
    if (threadIdx.x < H1) bias[threadIdx.x] = b1l[threadIdx.x];
    if (threadIdx.x < 2 * H1) sred[threadIdx.x] = 0.f;
    __syncthreads();

    int n = blockIdx.x * 256 + threadIdx.x;
    float acc[H1];
    if (n < N_NODES) {
        int o0 = off[n], o1 = off[n + 1];
        float mean[F_IN], own[F_IN];
#pragma unroll
        for (int k = 0; k < F_IN; ++k) mean[k] = 0.f;
        for (int i = o0; i < o1; ++i) {
            int s = srt[i];
            const float* xs = x + (long)s * F_IN;
#pragma unroll
            for (int k = 0; k < F_IN; ++k) mean[k] += xs[k];
        }
        float inv = 1.f / (float)max(o1 - o0, 1);
        const float* xo = x + (long)n * F_IN;
#pragma unroll
        for (int k = 0; k < F_IN; ++k) { mean[k] *= inv; own[k] = xo[k]; }
#pragma unroll
        for (int j = 0; j < H1; ++j) acc[j] = bias[j];
#pragma unroll
        for (int k = 0; k < F_IN; ++k) {
            float m = mean[k], o = own[k];
#pragma unroll
            for (int j = 0; j < H1; ++j) acc[j] += m * wl[j][k] + o * wr[j][k];
        }
        float* hp = h1 + (long)n * H1;
#pragma unroll
        for (int j = 0; j < H1; ++j) hp[j] = acc[j];
    } else {
#pragma unroll
        for (int j = 0; j < H1; ++j) acc[j] = 0.f;
    }
    // BN stats: wave-reduce each column over this wave's 64 nodes
#pragma unroll
    for (int j = 0; j < H1; ++j) {
        float v = acc[j], q = acc[j] * acc[j];
        for (int s = 32; s > 0; s >>= 1) {
            v += __shfl_down(v, s, 64);
            q += __shfl_down(q, s, 64);
        }
        if ((threadIdx.x & 63) == 0) {
            atomicAdd(&sred[j], v);
            atomicAdd(&sred[H1 + j], q);
        }
    }
    __syncthreads();
    if (threadIdx.x < 2 * H1) atomicAdd(&stats[threadIdx.x], sred[threadIdx.x]);
}

// ---------------- Layer 2: wave-per-node, d=64 -> 32 ----------------
// Applies BN1+ReLU lazily to h1_pre during gather; writes h2_pre; stats2.

__launch_bounds__(256)
__global__ void k_l2(const float* __restrict__ h1, const int* __restrict__ off,
                     const int* __restrict__ srt,
                     const float* __restrict__ W2l, const float* __restrict__ b2l,
                     const float* __restrict__ W2r,
                     const float* __restrict__ g1, const float* __restrict__ beta1,
                     const float* __restrict__ stats1,
                     float* __restrict__ h2, float* __restrict__ stats2) {
    __shared__ float meanb[4][H1], ownb[4][H1];
    __shared__ float sred[2 * H2];
    int lane = threadIdx.x & 63;
    int w = threadIdx.x >> 6;

    // BN params for layer-1 column `lane`
    float mu = stats1[lane] * (1.f / N_NODES);
    float var = stats1[H1 + lane] * (1.f / N_NODES) - mu * mu;
    float scale = rsqrtf(var + BN_EPS) * g1[lane];
    float shift = beta1[lane] - mu * scale;

    // lane j<32 holds W2l[j][*]; lane j>=32 holds W2r[j-32][*]
    float wcol[H1];
    const float* wsrc = (lane < H2) ? (W2l + lane * H1) : (W2r + (lane - H2) * H1);
#pragma unroll
    for (int k = 0; k < H1; ++k) wcol[k] = wsrc[k];
    float bj = b2l[lane & (H2 - 1)];

    if (threadIdx.x < 2 * H2) sred[threadIdx.x] = 0.f;
    __syncthreads();

    float pS = 0.f, pQ = 0.f;
    int n = blockIdx.x * 4 + w;
    if (n < N_NODES) {
        int o0 = off[n], o1 = off[n + 1];
        float sum = 0.f;
        for (int i = o0; i < o1; ++i) {
            int s = srt[i];
            float v = h1[(long)s * H1 + lane];          // coalesced 256B row
            sum += fmaxf(fmaf(v, scale, shift), 0.f);
        }
        float inv = 1.f / (float)max(o1 - o0, 1);
        meanb[w][lane] = sum * inv;
        ownb[w][lane] = fmaxf(fmaf(h1[(long)n * H1 + lane], scale, shift), 0.f);

        const float* bsel = (lane < H2) ? &meanb[w][0] : &ownb[w][0];
        float acc = (lane < H2) ? bj : 0.f;
#pragma unroll
        for (int k = 0; k < H1; ++k) acc += bsel[k] * wcol[k];
        float other = __shfl_xor(acc, 32, 64);
        if (lane < H2) {
            float hp = acc + other;
            h2[(long)n * H2 + lane] = hp;
            pS = hp; pQ = hp * hp;
        }
    }
    if (lane < H2) {
        atomicAdd(&sred[lane], pS);
        atomicAdd(&sred[H2 + lane], pQ);
    }
    __syncthreads();
    if (threadIdx.x < 2 * H2) atomicAdd(&stats2[threadIdx.x], sred[threadIdx.x]);
}

// ---------------- Layer 3: 2 nodes per wave, d=32 -> 2, log_softmax ----------------

__launch_bounds__(256)
__global__ void k_l3(const float* __restrict__ h2, const int* __restrict__ off,
                     const int* __restrict__ srt,
                     const float* __restrict__ W3l, const float* __restrict__ b3l,
                     const float* __restrict__ W3r,
                     const float* __restrict__ g2, const float* __restrict__ beta2,
                     const float* __restrict__ stats2, float* __restrict__ out) {
    int lane = threadIdx.x & 63;
    int w = threadIdx.x >> 6;
    int h = lane >> 5;
    int j = lane & 31;

    float mu = stats2[j] * (1.f / N_NODES);
    float var = stats2[H2 + j] * (1.f / N_NODES) - mu * mu;
    float scale = rsqrtf(var + BN_EPS) * g2[j];
    float shift = beta2[j] - mu * scale;

    float wl0 = W3l[j], wl1 = W3l[H2 + j];
    float wr0 = W3r[j], wr1 = W3r[H2 + j];
    float b0 = b3l[0], b1 = b3l[1];

    int n = (blockIdx.x * 4 + w) * 2 + h;
    if (n < N_NODES) {
        int o0 = off[n], o1 = off[n + 1];
        float sum = 0.f;
        for (int i = o0; i < o1; ++i) {
            int s = srt[i];
            float v = h2[(long)s * H2 + j];
            sum += fmaxf(fmaf(v, scale, shift), 0.f);
        }
        float inv = 1.f / (float)max(o1 - o0, 1);
        float meanj = sum * inv;
        float ownj = fmaxf(fmaf(h2[(long)n * H2 + j], scale, shift), 0.f);
        float p0 = meanj * wl0 + ownj * wr0;
        float p1 = meanj * wl1 + ownj * wr1;
#pragma unroll
        for (int s = 16; s > 0; s >>= 1) {
            p0 += __shfl_xor(p0, s, 32);
            p1 += __shfl_xor(p1, s, 32);
        }
        if (j == 0) {
            float z0 = p0 + b0, z1 = p1 + b1;
            float m = fmaxf(z0, z1);
            float l = m + logf(__expf(z0 - m) + __expf(z1 - m));
            out[(long)n * 2 + 0] = z0 - l;
            out[(long)n * 2 + 1] = z1 - l;
        }
    }
}

// ---------------- launch ----------------

extern "C" void kernel_launch(void* const* d_in, const int* in_sizes, int n_in,
                              void* d_out, int out_size, void* d_ws, size_t ws_size,
                              hipStream_t stream) {
    const float* x    = (const float*)d_in[0];
    const int*   ei   = (const int*)d_in[1];
    const float* W1l  = (const float*)d_in[2];
    const float* b1l  = (const float*)d_in[3];
    const float* W1r  = (const float*)d_in[4];
    const float* g1   = (const float*)d_in[5];
    const float* bt1  = (const float*)d_in[6];
    const float* W2l  = (const float*)d_in[7];
    const float* b2l  = (const float*)d_in[8];
    const float* W2r  = (const float*)d_in[9];
    const float* g2   = (const float*)d_in[10];
    const float* bt2  = (const float*)d_in[11];
    const float* W3l  = (const float*)d_in[12];
    const float* b3l  = (const float*)d_in[13];
    const float* W3r  = (const float*)d_in[14];
    float* out = (float*)d_out;

    // workspace layout (4B units)
    float* stats1 = (float*)d_ws;            // 128
    float* stats2 = stats1 + 128;            // 64 (+pad to 256)
    int* deg  = (int*)d_ws + 256;            // 100096
    int* off  = deg + 100096;                // 100096 (uses N+1)
    int* cur  = off + 100096;                // 100096
    int* srt  = cur + 100096;                // 1600000
    int* part = srt + 1600000;               // 256
    float* h1 = (float*)(part + 256);        // N*64
    float* h2 = h1 + (size_t)N_NODES * H1;   // N*32

    const int* srcv = ei;
    const int* dstv = ei + N_EDGES;

    // zero stats + degree counters
    hipMemsetAsync(d_ws, 0, (256 + 100096) * sizeof(int), stream);

    k_deg   <<<(N_EDGES + 255) / 256, 256, 0, stream>>>(dstv, deg);
    k_scan_a<<<98, 1024, 0, stream>>>(deg, off, part);
    k_scan_b<<<1, 128, 0, stream>>>(part, 98);
    k_scan_c<<<(N_NODES + 255) / 256, 256, 0, stream>>>(off, cur, part);
    k_fill  <<<(N_EDGES + 255) / 256, 256, 0, stream>>>(srcv, dstv, cur, srt);
    k_l1    <<<(N_NODES + 255) / 256, 256, 0, stream>>>(x, off, srt, W1l, b1l, W1r, h1, stats1);
    k_l2    <<<(N_NODES + 3) / 4, 256, 0, stream>>>(h1, off, srt, W2l, b2l, W2r, g1, bt1, stats1, h2, stats2);
    k_l3    <<<(N_NODES + 7) / 8, 256, 0, stream>>>(h2, off, srt, W3l, b3l, W3r, g2, bt2, stats2, out);
}

// Round 5
// 603.285 us; speedup vs baseline: 1.9378x; 1.9378x over previous
//
#include <hip/hip_runtime.h>
#include <hip/hip_bf16.h>
#include <math.h>

#define N_NODES 100000
#define N_EDGES 1600000
#define F_IN 15
#define H1 64
#define H2 32
#define BN_EPS 1e-5f
#define NBLK 2048            // grid-stride blocks for the layer kernels
#define RELU1(v) fmaxf(fmaf((v), scale, shift), 0.f)

// ---------------- CSR build ----------------

__global__ void k_deg(const int* __restrict__ dst, int* __restrict__ deg) {
    int e = blockIdx.x * blockDim.x + threadIdx.x;
    if (e < N_EDGES) atomicAdd(&deg[dst[e]], 1);
}

__global__ void k_scan_a(const int* __restrict__ deg, int* __restrict__ off,
                         int* __restrict__ part) {
    __shared__ int s[1024];
    int i = blockIdx.x * 1024 + threadIdx.x;
    int v = (i < N_NODES) ? deg[i] : 0;
    s[threadIdx.x] = v;
    __syncthreads();
    for (int o = 1; o < 1024; o <<= 1) {
        int t = (threadIdx.x >= o) ? s[threadIdx.x - o] : 0;
        __syncthreads();
        s[threadIdx.x] += t;
        __syncthreads();
    }
    if (i < N_NODES) off[i] = s[threadIdx.x] - v;   // block-local exclusive
    if (threadIdx.x == 1023) part[blockIdx.x] = s[1023];
}

__global__ void k_scan_b(int* __restrict__ part, int nb) {
    __shared__ int s[128];
    int v = (threadIdx.x < nb) ? part[threadIdx.x] : 0;
    s[threadIdx.x] = v;
    __syncthreads();
    for (int o = 1; o < 128; o <<= 1) {
        int t = (threadIdx.x >= o) ? s[threadIdx.x - o] : 0;
        __syncthreads();
        s[threadIdx.x] += t;
        __syncthreads();
    }
    if (threadIdx.x < nb) part[threadIdx.x] = s[threadIdx.x] - v;  // exclusive base
}

__global__ void k_scan_c(int* __restrict__ off, int* __restrict__ cur,
                         const int* __restrict__ part) {
    int i = blockIdx.x * blockDim.x + threadIdx.x;
    if (i < N_NODES) {
        int v = off[i] + part[i >> 10];
        off[i] = v;
        cur[i] = v;
    }
    if (i == 0) off[N_NODES] = N_EDGES;
}

__global__ void k_fill(const int* __restrict__ src, const int* __restrict__ dst,
                       int* __restrict__ cur, int* __restrict__ srt) {
    int e = blockIdx.x * blockDim.x + threadIdx.x;
    if (e < N_EDGES) {
        int p = atomicAdd(&cur[dst[e]], 1);
        srt[p] = src[e];
    }
}

// ---------------- Layer 1: wave-per-node, d=15 -> 64 ----------------
// Lanes 0..14 gather x rows (batch-8 MLP); same-wave LDS staging of mean/own;
// per-lane register weight rows; BN stats accumulated in registers.

__launch_bounds__(256)
__global__ void k_l1(const float* __restrict__ x, const int* __restrict__ off,
                     const int* __restrict__ srt,
                     const float* __restrict__ W1l, const float* __restrict__ b1l,
                     const float* __restrict__ W1r,
                     float* __restrict__ h1, float* __restrict__ stats) {
    __shared__ float m_lds[4][16], o_lds[4][16];
    __shared__ float sred[2 * H1];
    int lane = threadIdx.x & 63;
    int w = threadIdx.x >> 6;
    int gw = blockIdx.x * 4 + w;
    const int NW = NBLK * 4;

    // lane j holds W1l[j][*], W1r[j][*] (loop-invariant -> registers)
    float wl[F_IN], wr[F_IN];
#pragma unroll
    for (int k = 0; k < F_IN; ++k) {
        wl[k] = W1l[lane * F_IN + k];
        wr[k] = W1r[lane * F_IN + k];
    }
    float bj = b1l[lane];

    if (threadIdx.x < 2 * H1) sred[threadIdx.x] = 0.f;
    __syncthreads();

    float sS = 0.f, sQ = 0.f;
    for (int n = gw; n < N_NODES; n += NW) {
        int o0 = off[n], o1 = off[n + 1];
        float sum = 0.f;
        int i = o0;
        for (; i + 8 <= o1; i += 8) {
            int s0 = srt[i+0], s1 = srt[i+1], s2 = srt[i+2], s3 = srt[i+3],
                s4 = srt[i+4], s5 = srt[i+5], s6 = srt[i+6], s7 = srt[i+7];
            if (lane < F_IN) {
                float v0 = x[(long)s0*F_IN+lane], v1 = x[(long)s1*F_IN+lane],
                      v2 = x[(long)s2*F_IN+lane], v3 = x[(long)s3*F_IN+lane],
                      v4 = x[(long)s4*F_IN+lane], v5 = x[(long)s5*F_IN+lane],
                      v6 = x[(long)s6*F_IN+lane], v7 = x[(long)s7*F_IN+lane];
                sum += ((v0+v1)+(v2+v3)) + ((v4+v5)+(v6+v7));
            }
        }
        for (; i < o1; ++i) {
            int s = srt[i];
            if (lane < F_IN) sum += x[(long)s*F_IN+lane];
        }
        float inv = 1.f / (float)max(o1 - o0, 1);
        if (lane < F_IN) {
            m_lds[w][lane] = sum * inv;
            o_lds[w][lane] = x[(long)n*F_IN+lane];
        }
        // same-wave LDS write->read (pattern validated on HW in round 3)
        float acc = bj;
#pragma unroll
        for (int k = 0; k < F_IN; ++k)
            acc += m_lds[w][k] * wl[k] + o_lds[w][k] * wr[k];
        h1[(long)n*H1 + lane] = acc;
        sS += acc; sQ += acc * acc;
    }
    atomicAdd(&sred[lane], sS);
    atomicAdd(&sred[H1 + lane], sQ);
    __syncthreads();
    if (threadIdx.x < 2 * H1) atomicAdd(&stats[threadIdx.x], sred[threadIdx.x]);
}

// ---------------- Layer 2: wave-per-node, d=64 -> 32 ----------------
// Lazy BN1+ReLU during batch-8 gather; register weight column; LDS broadcast GEMM.

__launch_bounds__(256)
__global__ void k_l2(const float* __restrict__ h1, const int* __restrict__ off,
                     const int* __restrict__ srt,
                     const float* __restrict__ W2l, const float* __restrict__ b2l,
                     const float* __restrict__ W2r,
                     const float* __restrict__ g1, const float* __restrict__ beta1,
                     const float* __restrict__ stats1,
                     float* __restrict__ h2, float* __restrict__ stats2) {
    __shared__ float meanb[4][H1], ownb[4][H1];
    __shared__ float sred[2 * H2];
    int lane = threadIdx.x & 63;
    int w = threadIdx.x >> 6;
    int gw = blockIdx.x * 4 + w;
    const int NW = NBLK * 4;

    float mu = stats1[lane] * (1.f / N_NODES);
    float var = stats1[H1 + lane] * (1.f / N_NODES) - mu * mu;
    float scale = rsqrtf(var + BN_EPS) * g1[lane];
    float shift = beta1[lane] - mu * scale;

    // lane j<32 holds W2l[j][*]; lane j>=32 holds W2r[j-32][*] (loop-invariant)
    float wcol[H1];
    const float* wsrc = (lane < H2) ? (W2l + lane * H1) : (W2r + (lane - H2) * H1);
#pragma unroll
    for (int k = 0; k < H1; ++k) wcol[k] = wsrc[k];
    float bj = (lane < H2) ? b2l[lane] : 0.f;

    if (threadIdx.x < 2 * H2) sred[threadIdx.x] = 0.f;
    __syncthreads();

    float sS = 0.f, sQ = 0.f;
    for (int n = gw; n < N_NODES; n += NW) {
        int o0 = off[n], o1 = off[n + 1];
        float sum = 0.f;
        int i = o0;
        for (; i + 8 <= o1; i += 8) {
            int s0 = srt[i+0], s1 = srt[i+1], s2 = srt[i+2], s3 = srt[i+3],
                s4 = srt[i+4], s5 = srt[i+5], s6 = srt[i+6], s7 = srt[i+7];
            float v0 = h1[(long)s0*H1+lane], v1 = h1[(long)s1*H1+lane],
                  v2 = h1[(long)s2*H1+lane], v3 = h1[(long)s3*H1+lane],
                  v4 = h1[(long)s4*H1+lane], v5 = h1[(long)s5*H1+lane],
                  v6 = h1[(long)s6*H1+lane], v7 = h1[(long)s7*H1+lane];
            sum += ((RELU1(v0)+RELU1(v1)) + (RELU1(v2)+RELU1(v3)))
                 + ((RELU1(v4)+RELU1(v5)) + (RELU1(v6)+RELU1(v7)));
        }
        for (; i < o1; ++i) {
            int s = srt[i];
            sum += RELU1(h1[(long)s*H1+lane]);
        }
        float inv = 1.f / (float)max(o1 - o0, 1);
        meanb[w][lane] = sum * inv;
        ownb[w][lane] = RELU1(h1[(long)n*H1+lane]);

        const float* bsel = (lane < H2) ? &meanb[w][0] : &ownb[w][0];
        float acc = bj;
#pragma unroll
        for (int k = 0; k < H1; ++k) acc += bsel[k] * wcol[k];
        float other = __shfl_xor(acc, 32, 64);
        if (lane < H2) {
            float hp = acc + other;
            h2[(long)n*H2 + lane] = hp;
            sS += hp; sQ += hp * hp;
        }
    }
    if (lane < H2) {
        atomicAdd(&sred[lane], sS);
        atomicAdd(&sred[H2 + lane], sQ);
    }
    __syncthreads();
    if (threadIdx.x < 2 * H2) atomicAdd(&stats2[threadIdx.x], sred[threadIdx.x]);
}

// ---------------- Layer 3: 2 nodes per wave, d=32 -> 2, log_softmax ----------------

__launch_bounds__(256)
__global__ void k_l3(const float* __restrict__ h2, const int* __restrict__ off,
                     const int* __restrict__ srt,
                     const float* __restrict__ W3l, const float* __restrict__ b3l,
                     const float* __restrict__ W3r,
                     const float* __restrict__ g2, const float* __restrict__ beta2,
                     const float* __restrict__ stats2, float* __restrict__ out) {
    int lane = threadIdx.x & 63;
    int w = threadIdx.x >> 6;
    int h = lane >> 5;
    int j = lane & 31;
    int gw = blockIdx.x * 4 + w;
    const int NW = NBLK * 4;

    float mu = stats2[j] * (1.f / N_NODES);
    float var = stats2[H2 + j] * (1.f / N_NODES) - mu * mu;
    float scale = rsqrtf(var + BN_EPS) * g2[j];
    float shift = beta2[j] - mu * scale;

    float wl0 = W3l[j], wl1 = W3l[H2 + j];
    float wr0 = W3r[j], wr1 = W3r[H2 + j];
    float b0 = b3l[0], b1 = b3l[1];

    for (int p = gw; p < N_NODES / 2; p += NW) {
        int n = p * 2 + h;
        int o0 = off[n], o1 = off[n + 1];
        float sum = 0.f;
        int i = o0;
        for (; i + 8 <= o1; i += 8) {
            int s0 = srt[i+0], s1 = srt[i+1], s2 = srt[i+2], s3 = srt[i+3],
                s4 = srt[i+4], s5 = srt[i+5], s6 = srt[i+6], s7 = srt[i+7];
            float v0 = h2[(long)s0*H2+j], v1 = h2[(long)s1*H2+j],
                  v2 = h2[(long)s2*H2+j], v3 = h2[(long)s3*H2+j],
                  v4 = h2[(long)s4*H2+j], v5 = h2[(long)s5*H2+j],
                  v6 = h2[(long)s6*H2+j], v7 = h2[(long)s7*H2+j];
            sum += ((RELU1(v0)+RELU1(v1)) + (RELU1(v2)+RELU1(v3)))
                 + ((RELU1(v4)+RELU1(v5)) + (RELU1(v6)+RELU1(v7)));
        }
        for (; i < o1; ++i) {
            int s = srt[i];
            sum += RELU1(h2[(long)s*H2+j]);
        }
        float inv = 1.f / (float)max(o1 - o0, 1);
        float meanj = sum * inv;
        float ownj = RELU1(h2[(long)n*H2+j]);
        float p0 = meanj * wl0 + ownj * wr0;
        float p1 = meanj * wl1 + ownj * wr1;
#pragma unroll
        for (int s = 16; s > 0; s >>= 1) {
            p0 += __shfl_xor(p0, s, 32);
            p1 += __shfl_xor(p1, s, 32);
        }
        if (j == 0) {
            float z0 = p0 + b0, z1 = p1 + b1;
            float m = fmaxf(z0, z1);
            float l = m + logf(__expf(z0 - m) + __expf(z1 - m));
            out[(long)n * 2 + 0] = z0 - l;
            out[(long)n * 2 + 1] = z1 - l;
        }
    }
}

// ---------------- launch ----------------

extern "C" void kernel_launch(void* const* d_in, const int* in_sizes, int n_in,
                              void* d_out, int out_size, void* d_ws, size_t ws_size,
                              hipStream_t stream) {
    const float* x    = (const float*)d_in[0];
    const int*   ei   = (const int*)d_in[1];
    const float* W1l  = (const float*)d_in[2];
    const float* b1l  = (const float*)d_in[3];
    const float* W1r  = (const float*)d_in[4];
    const float* g1   = (const float*)d_in[5];
    const float* bt1  = (const float*)d_in[6];
    const float* W2l  = (const float*)d_in[7];
    const float* b2l  = (const float*)d_in[8];
    const float* W2r  = (const float*)d_in[9];
    const float* g2   = (const float*)d_in[10];
    const float* bt2  = (const float*)d_in[11];
    const float* W3l  = (const float*)d_in[12];
    const float* b3l  = (const float*)d_in[13];
    const float* W3r  = (const float*)d_in[14];
    float* out = (float*)d_out;

    // workspace layout (4B units)
    float* stats1 = (float*)d_ws;            // 128
    float* stats2 = stats1 + 128;            // 64 (+pad to 256)
    int* deg  = (int*)d_ws + 256;            // 100096
    int* off  = deg + 100096;                // 100096 (uses N+1)
    int* cur  = off + 100096;                // 100096
    int* srt  = cur + 100096;                // 1600000
    int* part = srt + 1600000;               // 256
    float* h1 = (float*)(part + 256);        // N*64
    float* h2 = h1 + (size_t)N_NODES * H1;   // N*32

    const int* srcv = ei;
    const int* dstv = ei + N_EDGES;

    // zero stats + degree counters
    hipMemsetAsync(d_ws, 0, (256 + 100096) * sizeof(int), stream);

    k_deg   <<<(N_EDGES + 255) / 256, 256, 0, stream>>>(dstv, deg);
    k_scan_a<<<98, 1024, 0, stream>>>(deg, off, part);
    k_scan_b<<<1, 128, 0, stream>>>(part, 98);
    k_scan_c<<<(N_NODES + 255) / 256, 256, 0, stream>>>(off, cur, part);
    k_fill  <<<(N_EDGES + 255) / 256, 256, 0, stream>>>(srcv, dstv, cur, srt);
    k_l1    <<<NBLK, 256, 0, stream>>>(x, off, srt, W1l, b1l, W1r, h1, stats1);
    k_l2    <<<NBLK, 256, 0, stream>>>(h1, off, srt, W2l, b2l, W2r, g1, bt1, stats1, h2, stats2);
    k_l3    <<<NBLK, 256, 0, stream>>>(h2, off, srt, W3l, b3l, W3r, g2, bt2, stats2, out);
}